// Round 1
// baseline (1746.859 us; speedup 1.0000x reference)
//
#include <hip/hip_runtime.h>

typedef _Float16 half8 __attribute__((ext_vector_type(8)));
typedef float f32x4 __attribute__((ext_vector_type(4)));

#define B_TOTAL 32768
#define T 7
#define F 36
#define U 256
#define G4 1024
#define BM 32          // batch rows per block
#define THREADS 512    // 8 waves
#define KC 10          // K chunks of 32: kc 0..7 = h (K=256), kc 8..9 = x (F=36 padded to 64)
#define H_STRIDE 264   // halves; 264*2=528 B rows, 16B-aligned

// Pack W into per-wave-contiguous fragment layout:
// Wq[w][kc][gnt][l15][kin], gnt = g*2 + nt, col = g*256 + w*32 + nt*16 + l15,
// k = kc*32 + kin.  Rows: k<256 -> Wr, 256<=k<292 -> Wk, else 0.
// Flattened: dst[bid*512 + tid] with bid = (w*KC + kc)*8 + gnt, tid = l15*32 + kin.
__global__ __launch_bounds__(512) void pack_w(const float* __restrict__ Wr,
                                              const float* __restrict__ Wk,
                                              _Float16* __restrict__ Wq) {
    const int bid = blockIdx.x;
    const int gnt = bid & 7;
    const int kc  = (bid >> 3) % KC;
    const int w   = (bid >> 3) / KC;
    const int tid = threadIdx.x;
    const int l15 = tid >> 5;
    const int kin = tid & 31;
    const int g  = gnt >> 1;
    const int nt = gnt & 1;
    const int col = g * 256 + w * 32 + nt * 16 + l15;
    const int k   = kc * 32 + kin;
    float v = 0.f;
    if (k < U)          v = Wr[(size_t)k * G4 + col];
    else if (k < U + F) v = Wk[(size_t)(k - U) * G4 + col];
    Wq[(size_t)bid * 512 + tid] = (_Float16)v;
}

__device__ __forceinline__ float fast_sigmoid(float x) {
    return __builtin_amdgcn_rcpf(1.f + __expf(-x));
}
__device__ __forceinline__ float fast_tanh(float x) {
    return 1.f - 2.f * __builtin_amdgcn_rcpf(1.f + __expf(2.f * x));
}

// Persistent LSTM: 8-wave block owns BM=32 batch rows for all T=7 steps.
// Wave w owns u-range [32w,32w+32) x 4 gates x all 32 rows:
//   acc[mt in 0..1][gnt = g*2+nt] with C-tile (row = mt*16+q*4+r, u = 32w+nt*16+l15).
// Double-buffered h in LDS -> ONE barrier per step. Two 8-wave blocks co-resident
// per CU (128 VGPR+AGPR) overlap each other's serial phases.
__global__ __launch_bounds__(512, 4) void lstm_kernel(
    const float* __restrict__ x,      // [B,T,F]
    const float* __restrict__ h0,     // [B,U]
    const float* __restrict__ c0,     // [B,U]
    const _Float16* __restrict__ Wq,  // packed [8][KC][8][16][32]
    const float* __restrict__ bias_g, // [G4]
    float* __restrict__ out)          // [B,T,U]
{
    __shared__ __align__(16) _Float16 hbuf[2][BM * H_STRIDE];

    const int tid  = threadIdx.x;
    const int lane = tid & 63;
    const int w    = tid >> 6;     // wave id 0..7 = u-tile
    const int l15  = lane & 15;
    const int q    = lane >> 4;    // 0..3
    const int u0   = w * 32;
    const int b0   = blockIdx.x * BM;

    // --- stage h0 -> LDS fp16 ---
    for (int i = tid; i < BM * U; i += THREADS) {
        int m = i >> 8, u = i & 255;
        hbuf[0][m * H_STRIDE + u] = (_Float16)h0[(size_t)b0 * U + i];
    }
    // --- c0 into registers ---
    float c[2][2][4];
    #pragma unroll
    for (int mt = 0; mt < 2; ++mt)
        #pragma unroll
        for (int nt = 0; nt < 2; ++nt)
            #pragma unroll
            for (int r = 0; r < 4; ++r) {
                int row = mt * 16 + q * 4 + r;
                c[mt][nt][r] = c0[(size_t)(b0 + row) * U + u0 + nt * 16 + l15];
            }
    // --- bias per (gate, n-tile) ---
    float bv[4][2];
    #pragma unroll
    for (int g = 0; g < 4; ++g)
        #pragma unroll
        for (int nt = 0; nt < 2; ++nt)
            bv[g][nt] = bias_g[g * 256 + u0 + nt * 16 + l15];

    // per-lane W base (halves): wave slice + lane offset
    const _Float16* wbase = Wq + (size_t)w * (KC * 8 * 512) + (l15 * 32 + q * 8);

    __syncthreads();

    int cur = 0;
    #pragma unroll 1
    for (int t = 0; t < T; ++t) {
        f32x4 acc[2][8];   // [m_tile][gnt]
        #pragma unroll
        for (int mt = 0; mt < 2; ++mt)
            #pragma unroll
            for (int gnt = 0; gnt < 8; ++gnt) {
                float v = bv[gnt >> 1][gnt & 1];
                acc[mt][gnt] = (f32x4){v, v, v, v};
            }

        // --- h part: kc 0..7, A from LDS, B from packed W (L2-resident) ---
        #pragma unroll
        for (int kc = 0; kc < 8; ++kc) {
            half8 a0 = *(const half8*)&hbuf[cur][(l15)      * H_STRIDE + kc * 32 + q * 8];
            half8 a1 = *(const half8*)&hbuf[cur][(16 + l15) * H_STRIDE + kc * 32 + q * 8];
            half8 bfr[4];
            #pragma unroll
            for (int gnt = 0; gnt < 4; ++gnt)
                bfr[gnt] = *(const half8*)(wbase + (size_t)(kc * 8 + gnt) * 512);
            #pragma unroll
            for (int gnt = 0; gnt < 4; ++gnt) {
                acc[0][gnt] = __builtin_amdgcn_mfma_f32_16x16x32_f16(a0, bfr[gnt], acc[0][gnt], 0, 0, 0);
                acc[1][gnt] = __builtin_amdgcn_mfma_f32_16x16x32_f16(a1, bfr[gnt], acc[1][gnt], 0, 0, 0);
            }
            #pragma unroll
            for (int gnt = 0; gnt < 4; ++gnt)
                bfr[gnt] = *(const half8*)(wbase + (size_t)(kc * 8 + 4 + gnt) * 512);
            #pragma unroll
            for (int gnt = 0; gnt < 4; ++gnt) {
                acc[0][4 + gnt] = __builtin_amdgcn_mfma_f32_16x16x32_f16(a0, bfr[gnt], acc[0][4 + gnt], 0, 0, 0);
                acc[1][4 + gnt] = __builtin_amdgcn_mfma_f32_16x16x32_f16(a1, bfr[gnt], acc[1][4 + gnt], 0, 0, 0);
            }
        }

        // --- x part: kc 8,9 — A built in regs straight from global fp32 x ---
        half8 xf[2], xg[2];
        #pragma unroll
        for (int mt = 0; mt < 2; ++mt) {
            const float* xr = x + ((size_t)(b0 + mt * 16 + l15) * T + t) * F;
            f32x4 v0 = *(const f32x4*)(xr + q * 8);       // f = q*8 .. q*8+3   (all < 32)
            f32x4 v1 = *(const f32x4*)(xr + q * 8 + 4);   // f = q*8+4 .. q*8+7
            half8 hv;
            #pragma unroll
            for (int j = 0; j < 4; ++j) { hv[j] = (_Float16)v0[j]; hv[4 + j] = (_Float16)v1[j]; }
            xf[mt] = hv;
            half8 hz;
            #pragma unroll
            for (int j = 0; j < 8; ++j) hz[j] = (_Float16)0.f;
            if (q == 0) {                                  // f = 32..35 real, 36..39 zero
                f32x4 v2 = *(const f32x4*)(xr + 32);
                #pragma unroll
                for (int j = 0; j < 4; ++j) hz[j] = (_Float16)v2[j];
            }
            xg[mt] = hz;
        }
        #pragma unroll
        for (int gnt = 0; gnt < 8; ++gnt) {
            half8 b8 = *(const half8*)(wbase + (size_t)(8 * 8 + gnt) * 512);
            acc[0][gnt] = __builtin_amdgcn_mfma_f32_16x16x32_f16(xf[0], b8, acc[0][gnt], 0, 0, 0);
            acc[1][gnt] = __builtin_amdgcn_mfma_f32_16x16x32_f16(xf[1], b8, acc[1][gnt], 0, 0, 0);
        }
        #pragma unroll
        for (int gnt = 0; gnt < 8; ++gnt) {
            half8 b9 = *(const half8*)(wbase + (size_t)(9 * 8 + gnt) * 512);
            acc[0][gnt] = __builtin_amdgcn_mfma_f32_16x16x32_f16(xg[0], b9, acc[0][gnt], 0, 0, 0);
            acc[1][gnt] = __builtin_amdgcn_mfma_f32_16x16x32_f16(xg[1], b9, acc[1][gnt], 0, 0, 0);
        }

        // --- gates; write h_{t+1} fp16 to other LDS buffer; store out fp32 direct ---
        const int nxt = cur ^ 1;
        #pragma unroll
        for (int mt = 0; mt < 2; ++mt)
            #pragma unroll
            for (int nt = 0; nt < 2; ++nt)
                #pragma unroll
                for (int r = 0; r < 4; ++r) {
                    float zi = acc[mt][0 + nt][r];
                    float zf = acc[mt][2 + nt][r];
                    float zg = acc[mt][4 + nt][r];
                    float zo = acc[mt][6 + nt][r];
                    float ig = fast_sigmoid(zi);
                    float fg = fast_sigmoid(zf);
                    float gg = fast_tanh(zg);
                    float og = fast_sigmoid(zo);
                    float cn = fg * c[mt][nt][r] + ig * gg;
                    c[mt][nt][r] = cn;
                    float hv = og * fast_tanh(cn);
                    int row = mt * 16 + q * 4 + r;
                    hbuf[nxt][row * H_STRIDE + u0 + nt * 16 + l15] = (_Float16)hv;
                    out[((size_t)(b0 + row) * T + t) * U + u0 + nt * 16 + l15] = hv;
                }

        __syncthreads();   // writes to hbuf[nxt] visible; readers of hbuf[cur] done
        cur = nxt;
    }
}

extern "C" void kernel_launch(void* const* d_in, const int* in_sizes, int n_in,
                              void* d_out, int out_size, void* d_ws, size_t ws_size,
                              hipStream_t stream) {
    const float* x  = (const float*)d_in[0];
    const float* h0 = (const float*)d_in[1];
    const float* c0 = (const float*)d_in[2];
    const float* Wk = (const float*)d_in[3];
    const float* Wr = (const float*)d_in[4];
    const float* b  = (const float*)d_in[5];
    float* out = (float*)d_out;

    _Float16* Wq = (_Float16*)d_ws;   // 8*10*8*512*2 = 640 KB

    pack_w<<<8 * KC * 8, 512, 0, stream>>>(Wr, Wk, Wq);
    lstm_kernel<<<B_TOTAL / BM, 512, 0, stream>>>(x, h0, c0, Wq, b, out);
}

// Round 4
// 1598.269 us; speedup vs baseline: 1.0930x; 1.0930x over previous
//
#include <hip/hip_runtime.h>

typedef _Float16 half8 __attribute__((ext_vector_type(8)));
typedef float f32x4 __attribute__((ext_vector_type(4)));

#define B_TOTAL 32768
#define T 7
#define F 36
#define U 256
#define G4 1024
#define BM 32          // batch rows per block
#define THREADS 512    // 8 waves
#define KC 10          // K chunks of 32: kc 0..7 = h (K=256), kc 8..9 = x (F=36 padded to 64)
#define H_STRIDE 264   // halves; 264*2=528 B rows, 16B-aligned
#define XS 72          // halves per (t,row) in x LDS: f 0..63 used (36 real + 28 zero), pad to 72

// Pack W into per-wave-contiguous fragment layout:
// Wq[w][kc][gnt][l15][kin], gnt = g*2 + nt, col = g*256 + w*32 + nt*16 + l15,
// k = kc*32 + kin.  Rows: k<256 -> Wr, 256<=k<292 -> Wk, else 0.
__global__ __launch_bounds__(512) void pack_w(const float* __restrict__ Wr,
                                              const float* __restrict__ Wk,
                                              _Float16* __restrict__ Wq) {
    const int bid = blockIdx.x;
    const int gnt = bid & 7;
    const int kc  = (bid >> 3) % KC;
    const int w   = (bid >> 3) / KC;
    const int tid = threadIdx.x;
    const int l15 = tid >> 5;
    const int kin = tid & 31;
    const int g  = gnt >> 1;
    const int nt = gnt & 1;
    const int col = g * 256 + w * 32 + nt * 16 + l15;
    const int k   = kc * 32 + kin;
    float v = 0.f;
    if (k < U)          v = Wr[(size_t)k * G4 + col];
    else if (k < U + F) v = Wk[(size_t)(k - U) * G4 + col];
    Wq[(size_t)bid * 512 + tid] = (_Float16)v;
}

__device__ __forceinline__ float fast_sigmoid(float x) {
    return __builtin_amdgcn_rcpf(1.f + __expf(-x));
}
__device__ __forceinline__ float fast_tanh(float x) {
    return 1.f - 2.f * __builtin_amdgcn_rcpf(1.f + __expf(2.f * x));
}

// Persistent LSTM: 8-wave block owns BM=32 batch rows for all T=7 steps.
// Wave w owns u-range [32w,32w+32) x 4 gates x all 32 rows.
// Double-buffered h in LDS -> ONE barrier per step. Two 8-wave blocks per CU
// overlap each other's serial phases. All x staged in LDS once (fp16).
// Out-store: coalesced LDS-readback (full 128B lines), fire-and-forget.
__global__ __launch_bounds__(512, 4) void lstm_kernel(
    const float* __restrict__ x,      // [B,T,F]
    const float* __restrict__ h0,     // [B,U]
    const float* __restrict__ c0,     // [B,U]
    const _Float16* __restrict__ Wq,  // packed [8][KC][8][16][32]
    const float* __restrict__ bias_g, // [G4]
    float* __restrict__ out)          // [B,T,U]
{
    __shared__ __align__(16) _Float16 hbuf[2][BM * H_STRIDE];
    __shared__ __align__(16) _Float16 xs[T * BM * XS];

    const int tid  = threadIdx.x;
    const int lane = tid & 63;
    const int w    = tid >> 6;     // wave id 0..7 = u-tile
    const int l15  = lane & 15;
    const int q    = lane >> 4;    // 0..3
    const int u0   = w * 32;
    const int b0   = blockIdx.x * BM;

    // --- zero xs (covers the f=36..63 pad that MFMA reads, and row pad) ---
    {
        half8 z = {};
        for (int i = tid * 8; i < T * BM * XS; i += THREADS * 8)
            *(half8*)&xs[i] = z;
    }
    __syncthreads();   // zero visible before x-fill overlaps it

    // --- stage h0 -> LDS fp16 ---
    for (int i = tid; i < BM * U; i += THREADS) {
        int m = i >> 8, u = i & 255;
        hbuf[0][m * H_STRIDE + u] = (_Float16)h0[(size_t)b0 * U + i];
    }
    // --- stage ALL x for this block's rows: contiguous 32KB global read ---
    // x rows are contiguous: row has 252 floats. xs[t][row][f] <- x[row][t*36+f].
    for (int i = tid; i < BM * (T * F); i += THREADS) {
        int row = i / (T * F);
        int rem = i - row * (T * F);
        int t   = rem / F;
        int f   = rem - t * F;
        xs[(t * BM + row) * XS + f] = (_Float16)x[(size_t)(b0 + row) * (T * F) + rem];
    }
    // --- c0 into registers ---
    float c[2][2][4];
    #pragma unroll
    for (int mt = 0; mt < 2; ++mt)
        #pragma unroll
        for (int nt = 0; nt < 2; ++nt)
            #pragma unroll
            for (int r = 0; r < 4; ++r) {
                int row = mt * 16 + q * 4 + r;
                c[mt][nt][r] = c0[(size_t)(b0 + row) * U + u0 + nt * 16 + l15];
            }
    // --- bias per (gate, n-tile) ---
    float bv[4][2];
    #pragma unroll
    for (int g = 0; g < 4; ++g)
        #pragma unroll
        for (int nt = 0; nt < 2; ++nt)
            bv[g][nt] = bias_g[g * 256 + u0 + nt * 16 + l15];

    // per-lane W base (halves): wave slice + lane offset
    const _Float16* wbase = Wq + (size_t)w * (KC * 8 * 512) + (l15 * 32 + q * 8);

    __syncthreads();

    int cur = 0;
    #pragma unroll 1
    for (int t = 0; t < T; ++t) {
        f32x4 acc[2][8];   // [m_tile][gnt]
        #pragma unroll
        for (int mt = 0; mt < 2; ++mt)
            #pragma unroll
            for (int gnt = 0; gnt < 8; ++gnt) {
                float v = bv[gnt >> 1][gnt & 1];
                acc[mt][gnt] = (f32x4){v, v, v, v};
            }

        // --- h part: kc 0..7, A from LDS, B streamed from L2 ---
        #pragma unroll
        for (int kc = 0; kc < 8; ++kc) {
            half8 a0 = *(const half8*)&hbuf[cur][(l15)      * H_STRIDE + kc * 32 + q * 8];
            half8 a1 = *(const half8*)&hbuf[cur][(16 + l15) * H_STRIDE + kc * 32 + q * 8];
            half8 bfr[4];
            #pragma unroll
            for (int gnt = 0; gnt < 4; ++gnt)
                bfr[gnt] = *(const half8*)(wbase + (size_t)(kc * 8 + gnt) * 512);
            #pragma unroll
            for (int gnt = 0; gnt < 4; ++gnt) {
                acc[0][gnt] = __builtin_amdgcn_mfma_f32_16x16x32_f16(a0, bfr[gnt], acc[0][gnt], 0, 0, 0);
                acc[1][gnt] = __builtin_amdgcn_mfma_f32_16x16x32_f16(a1, bfr[gnt], acc[1][gnt], 0, 0, 0);
            }
            #pragma unroll
            for (int gnt = 0; gnt < 4; ++gnt)
                bfr[gnt] = *(const half8*)(wbase + (size_t)(kc * 8 + 4 + gnt) * 512);
            #pragma unroll
            for (int gnt = 0; gnt < 4; ++gnt) {
                acc[0][4 + gnt] = __builtin_amdgcn_mfma_f32_16x16x32_f16(a0, bfr[gnt], acc[0][4 + gnt], 0, 0, 0);
                acc[1][4 + gnt] = __builtin_amdgcn_mfma_f32_16x16x32_f16(a1, bfr[gnt], acc[1][4 + gnt], 0, 0, 0);
            }
        }

        // --- x part: kc 8 (f 0..31) and kc 9 (f 32..63, zeros past 35), A from LDS ---
        {
            half8 xa0 = *(const half8*)&xs[(t * BM + l15)      * XS + q * 8];
            half8 xa1 = *(const half8*)&xs[(t * BM + 16 + l15) * XS + q * 8];
            #pragma unroll
            for (int gnt = 0; gnt < 8; ++gnt) {
                half8 b8 = *(const half8*)(wbase + (size_t)(8 * 8 + gnt) * 512);
                acc[0][gnt] = __builtin_amdgcn_mfma_f32_16x16x32_f16(xa0, b8, acc[0][gnt], 0, 0, 0);
                acc[1][gnt] = __builtin_amdgcn_mfma_f32_16x16x32_f16(xa1, b8, acc[1][gnt], 0, 0, 0);
            }
            half8 xb0 = *(const half8*)&xs[(t * BM + l15)      * XS + 32 + q * 8];
            half8 xb1 = *(const half8*)&xs[(t * BM + 16 + l15) * XS + 32 + q * 8];
            #pragma unroll
            for (int gnt = 0; gnt < 8; ++gnt) {
                half8 b9 = *(const half8*)(wbase + (size_t)(9 * 8 + gnt) * 512);
                acc[0][gnt] = __builtin_amdgcn_mfma_f32_16x16x32_f16(xb0, b9, acc[0][gnt], 0, 0, 0);
                acc[1][gnt] = __builtin_amdgcn_mfma_f32_16x16x32_f16(xb1, b9, acc[1][gnt], 0, 0, 0);
            }
        }

        // --- gates; write h_{t+1} fp16 to other LDS buffer ---
        const int nxt = cur ^ 1;
        #pragma unroll
        for (int mt = 0; mt < 2; ++mt)
            #pragma unroll
            for (int nt = 0; nt < 2; ++nt)
                #pragma unroll
                for (int r = 0; r < 4; ++r) {
                    float zi = acc[mt][0 + nt][r];
                    float zf = acc[mt][2 + nt][r];
                    float zg = acc[mt][4 + nt][r];
                    float zo = acc[mt][6 + nt][r];
                    float ig = fast_sigmoid(zi);
                    float fg = fast_sigmoid(zf);
                    float gg = fast_tanh(zg);
                    float og = fast_sigmoid(zo);
                    float cn = fg * c[mt][nt][r] + ig * gg;
                    c[mt][nt][r] = cn;
                    float hv = og * fast_tanh(cn);
                    int row = mt * 16 + q * 4 + r;
                    hbuf[nxt][row * H_STRIDE + u0 + nt * 16 + l15] = (_Float16)hv;
                }

        __syncthreads();   // h_{t+1} complete & visible; readers of hbuf[cur] done

        // --- coalesced out-store from hbuf[nxt]: consecutive tids -> consecutive
        // 32B -> full 128B lines (no write-allocate RMW). Fire-and-forget:
        // overlaps next step's K-loop; next write to hbuf[nxt] is 2 barriers away.
        #pragma unroll
        for (int rb = 0; rb < 2; ++rb) {
            int j   = tid + rb * THREADS;   // 0..1023 chunks of 8 floats
            int row = j >> 5;
            int uo  = (j & 31) * 8;
            half8 hv = *(const half8*)&hbuf[nxt][row * H_STRIDE + uo];
            f32x4 lo = { (float)hv[0], (float)hv[1], (float)hv[2], (float)hv[3] };
            f32x4 hi = { (float)hv[4], (float)hv[5], (float)hv[6], (float)hv[7] };
            float* dst = out + ((size_t)(b0 + row) * T + t) * U + uo;
            *(f32x4*)dst       = lo;
            *(f32x4*)(dst + 4) = hi;
        }

        cur = nxt;
    }
}

extern "C" void kernel_launch(void* const* d_in, const int* in_sizes, int n_in,
                              void* d_out, int out_size, void* d_ws, size_t ws_size,
                              hipStream_t stream) {
    const float* x  = (const float*)d_in[0];
    const float* h0 = (const float*)d_in[1];
    const float* c0 = (const float*)d_in[2];
    const float* Wk = (const float*)d_in[3];
    const float* Wr = (const float*)d_in[4];
    const float* b  = (const float*)d_in[5];
    float* out = (float*)d_out;

    _Float16* Wq = (_Float16*)d_ws;   // 8*10*8*512*2 = 640 KB

    pack_w<<<8 * KC * 8, 512, 0, stream>>>(Wr, Wk, Wq);
    lstm_kernel<<<B_TOTAL / BM, 512, 0, stream>>>(x, h0, c0, Wq, b, out);
}

// Round 5
// 486.229 us; speedup vs baseline: 3.5927x; 3.2871x over previous
//
#include <hip/hip_runtime.h>

typedef _Float16 half8 __attribute__((ext_vector_type(8)));
typedef float f32x4 __attribute__((ext_vector_type(4)));

#define B_TOTAL 32768
#define T 7
#define F 36
#define U 256
#define G4 1024
#define BM 64
#define KC 10          // K chunks of 32: kc 0..7 = h (K=256), kc 8..9 = x (F=36 padded to 64)
#define KPACK 32
#define H_STRIDE 264   // halves; 264*2=528 B rows, 16B-aligned
#define XS 72          // halves per (t,row) in xs plane; 144 B stride -> 2-way bank aliasing only

// Round-0 verified W layout: Wq[kc][n][kin] fp16, n = gate*256 + u.
// W = [Wr (256 rows); Wk (36 rows); zeros (28 rows)].
__global__ __launch_bounds__(1024) void pack_w(const float* __restrict__ Wr,
                                               const float* __restrict__ Wk,
                                               _Float16* __restrict__ Wq) {
    const int kc   = blockIdx.x >> 2;
    const int kin0 = (blockIdx.x & 3) * 8;
    const int n    = threadIdx.x;
    _Float16* dst = Wq + ((size_t)kc * G4 + n) * KPACK + kin0;
    #pragma unroll
    for (int j = 0; j < 8; ++j) {
        int k = kc * KPACK + kin0 + j;
        float v = 0.f;
        if (k < U)          v = Wr[(size_t)k * G4 + n];
        else if (k < U + F) v = Wk[(size_t)(k - U) * G4 + n];
        dst[j] = (_Float16)v;
    }
}

__device__ __forceinline__ float fast_sigmoid(float x) {
    return __builtin_amdgcn_rcpf(1.f + __expf(-x));
}
__device__ __forceinline__ float fast_tanh(float x) {
    return 1.f - 2.f * __builtin_amdgcn_rcpf(1.f + __expf(2.f * x));
}

// Persistent LSTM, round-0 structure: one 16-wave block owns BM=64 batch rows
// for all T=7 steps. Wave w (of 16) owns u-range [16w,16w+16) x 4 gates x 64 rows.
// Deltas vs round 0: (1) double-buffered h in LDS -> ONE barrier/step (was 2);
// (2) all 7 x-steps staged in LDS once (no per-step global x prefetch).
// W layout/access and out-store are round-0 verbatim (verified L2-resident).
__global__ __launch_bounds__(1024) void lstm_kernel(
    const float* __restrict__ x,      // [B,T,F]
    const float* __restrict__ h0,     // [B,U]
    const float* __restrict__ c0,     // [B,U]
    const _Float16* __restrict__ Wq,  // packed [KC][G4][KPACK]
    const float* __restrict__ bias_g, // [G4]
    float* __restrict__ out)          // [B,T,U]
{
    __shared__ __align__(16) _Float16 hbuf[2][BM * H_STRIDE];  // 2 x 33.8 KB
    __shared__ __align__(16) _Float16 xs[T * BM * XS];          // 64.5 KB

    const int tid  = threadIdx.x;
    const int lane = tid & 63;
    const int w    = tid >> 6;     // wave id 0..15 = u-tile
    const int l15  = lane & 15;
    const int q    = lane >> 4;    // 0..3
    const int u0   = w * 16;
    const int b0   = blockIdx.x * BM;

    // --- zero xs (covers the f=36..63 pad the MFMA reads, and row pad) ---
    {
        half8 z = {};
        for (int i = tid * 8; i < T * BM * XS; i += 1024 * 8)
            *(half8*)&xs[i] = z;
    }
    __syncthreads();   // zero visible before fill

    // --- stage h0 -> LDS fp16 ---
    for (int i = tid; i < BM * U; i += 1024) {
        int m = i >> 8, u = i & 255;
        hbuf[0][m * H_STRIDE + u] = (_Float16)h0[(size_t)b0 * U + i];
    }
    // --- stage ALL x for this block's rows (contiguous 64KB global read) ---
    // xs[t][row][f] <- x[row][t*F + f]; row has T*F=252 contiguous floats.
    for (int i = tid; i < BM * (T * F); i += 1024) {
        int row = i / (T * F);
        int rem = i - row * (T * F);
        int t   = rem / F;
        int f   = rem - t * F;
        xs[(t * BM + row) * XS + f] = (_Float16)x[(size_t)(b0 + row) * (T * F) + rem];
    }
    // --- c0 into registers: lane holds (u = u0+l15) for rows mt*16+q*4+r ---
    float c[16];
    #pragma unroll
    for (int mt = 0; mt < 4; ++mt)
        #pragma unroll
        for (int r = 0; r < 4; ++r) {
            int row = mt * 16 + q * 4 + r;
            c[mt * 4 + r] = c0[(size_t)(b0 + row) * U + u0 + l15];
        }
    // --- bias per gate ---
    float bv[4];
    #pragma unroll
    for (int g = 0; g < 4; ++g) bv[g] = bias_g[g * U + u0 + l15];

    __syncthreads();

    int cur = 0;
    #pragma unroll 1
    for (int t = 0; t < T; ++t) {
        f32x4 acc[4][4];   // [m_tile][gate]
        #pragma unroll
        for (int mt = 0; mt < 4; ++mt)
            #pragma unroll
            for (int g = 0; g < 4; ++g)
                acc[mt][g] = (f32x4){bv[g], bv[g], bv[g], bv[g]};

        // --- K loop: z[64,1024] = h@Wr + x_t@Wk + b (round-0 W access) ---
        #pragma unroll 2
        for (int kc = 0; kc < KC; ++kc) {
            half8 bf[4];
            #pragma unroll
            for (int g = 0; g < 4; ++g) {
                size_t off = ((size_t)kc * G4 + g * U + u0 + l15) * KPACK + q * 8;
                bf[g] = *(const half8*)(Wq + off);
            }
            #pragma unroll
            for (int mt = 0; mt < 4; ++mt) {
                half8 af;
                if (kc < 8)
                    af = *(const half8*)&hbuf[cur][(mt * 16 + l15) * H_STRIDE + kc * 32 + q * 8];
                else
                    af = *(const half8*)&xs[(t * BM + mt * 16 + l15) * XS + (kc - 8) * 32 + q * 8];
                #pragma unroll
                for (int g = 0; g < 4; ++g)
                    acc[mt][g] = __builtin_amdgcn_mfma_f32_16x16x32_f16(af, bf[g], acc[mt][g], 0, 0, 0);
            }
        }

        // --- gates: i,f,g,o for (row,u) all live in the same lane ---
        const int nxt = cur ^ 1;
        #pragma unroll
        for (int mt = 0; mt < 4; ++mt)
            #pragma unroll
            for (int r = 0; r < 4; ++r) {
                float zi = acc[mt][0][r];
                float zf = acc[mt][1][r];
                float zg = acc[mt][2][r];
                float zo = acc[mt][3][r];
                float ig = fast_sigmoid(zi);
                float fg = fast_sigmoid(zf);
                float gg = fast_tanh(zg);
                float og = fast_sigmoid(zo);
                float cn = fg * c[mt * 4 + r] + ig * gg;
                c[mt * 4 + r] = cn;
                float hv = og * fast_tanh(cn);
                int row = mt * 16 + q * 4 + r;
                hbuf[nxt][row * H_STRIDE + u0 + l15] = (_Float16)hv;
            }

        __syncthreads();   // single barrier: h_{t+1} visible; K-loop readers of hbuf[cur] done

        // --- coalesced out-store from hbuf[nxt] (round-0 verbatim): consecutive
        // tids -> consecutive 32B -> full 128B lines. Fire-and-forget: overlaps
        // next step's K-loop; hbuf[nxt] is next overwritten at step t+2's gate
        // phase, which is 2 barriers after these reads were issued+waited.
        #pragma unroll
        for (int rb = 0; rb < 2; ++rb) {
            int j   = tid + rb * 1024;      // 0..2047 chunks of 8 floats
            int row = j >> 5;
            int uo  = (j & 31) * 8;
            half8 hv = *(const half8*)&hbuf[nxt][row * H_STRIDE + uo];
            f32x4 lo = { (float)hv[0], (float)hv[1], (float)hv[2], (float)hv[3] };
            f32x4 hi = { (float)hv[4], (float)hv[5], (float)hv[6], (float)hv[7] };
            float* dst = out + ((size_t)(b0 + row) * T + t) * U + uo;
            *(f32x4*)dst       = lo;
            *(f32x4*)(dst + 4) = hi;
        }

        cur = nxt;
    }
}

extern "C" void kernel_launch(void* const* d_in, const int* in_sizes, int n_in,
                              void* d_out, int out_size, void* d_ws, size_t ws_size,
                              hipStream_t stream) {
    const float* x  = (const float*)d_in[0];
    const float* h0 = (const float*)d_in[1];
    const float* c0 = (const float*)d_in[2];
    const float* Wk = (const float*)d_in[3];
    const float* Wr = (const float*)d_in[4];
    const float* b  = (const float*)d_in[5];
    float* out = (float*)d_out;

    _Float16* Wq = (_Float16*)d_ws;   // KC*G4*KPACK*2 = 640 KB

    pack_w<<<KC * 4, 1024, 0, stream>>>(Wr, Wk, Wq);
    lstm_kernel<<<B_TOTAL / BM, 1024, 0, stream>>>(x, h0, c0, Wq, b, out);
}